// Round 12
// baseline (442.614 us; speedup 1.0000x reference)
//
#include <hip/hip_runtime.h>
#include <cmath>

#define N_TOK 4096
#define DDIM 1024
#define FDIM 4096
#define NEXP 8
#define MAXT 72
#define MAXROWS (MAXT * 128)

typedef __attribute__((ext_vector_type(4))) float f32x4;
typedef __attribute__((ext_vector_type(8))) __bf16 bf16x8;
typedef __attribute__((ext_vector_type(4))) unsigned short us4;
typedef __attribute__((ext_vector_type(8))) unsigned short us8;

__device__ __forceinline__ unsigned short f2bf(float f) {
  unsigned u = __builtin_bit_cast(unsigned, f);
  u += 0x7FFFu + ((u >> 16) & 1u);
  return (unsigned short)(u >> 16);
}

__device__ __forceinline__ void gload16(const void* g, void* l) {
  __builtin_amdgcn_global_load_lds(
      (const __attribute__((address_space(1))) unsigned int*)g,
      (__attribute__((address_space(3))) unsigned int*)l, 16, 0, 0);
}

// ---------------- router: logits -> softmax -> top2 (+ fused x->bf16) ----------------
__global__ __launch_bounds__(64) void router_kernel(
    const float* __restrict__ x, const float* __restrict__ wg,
    float* __restrict__ probs, int* __restrict__ eids, float* __restrict__ ewts,
    unsigned short* __restrict__ xb) {
  int n = blockIdx.x;
  int t = threadIdx.x;
  const float* xr = x + (size_t)n * DDIM;
  f32x4 xv[4];
#pragma unroll
  for (int j = 0; j < 4; j++) xv[j] = *(const f32x4*)(xr + j * 256 + t * 4);
  float acc[8] = {0, 0, 0, 0, 0, 0, 0, 0};
#pragma unroll
  for (int j = 0; j < 4; j++) {
#pragma unroll
    for (int u = 0; u < 4; u++) {
      float v = xv[j][u];
      const float* wr = wg + (size_t)(j * 256 + t * 4 + u) * 8;
#pragma unroll
      for (int e = 0; e < 8; e++) acc[e] = fmaf(v, wr[e], acc[e]);
    }
  }
  unsigned short* xo = xb + (size_t)n * DDIM;
#pragma unroll
  for (int j = 0; j < 4; j++) {
    us4 o = {f2bf(xv[j][0]), f2bf(xv[j][1]), f2bf(xv[j][2]), f2bf(xv[j][3])};
    *(us4*)(xo + j * 256 + t * 4) = o;
  }
#pragma unroll
  for (int off = 32; off > 0; off >>= 1) {
#pragma unroll
    for (int e = 0; e < 8; e++) acc[e] += __shfl_xor(acc[e], off, 64);
  }
  if (t == 0) {
    float mx = acc[0];
#pragma unroll
    for (int e = 1; e < 8; e++) mx = fmaxf(mx, acc[e]);
    float p[8], s = 0.f;
#pragma unroll
    for (int e = 0; e < 8; e++) { p[e] = expf(acc[e] - mx); s += p[e]; }
    float inv = 1.f / s;
#pragma unroll
    for (int e = 0; e < 8; e++) { p[e] *= inv; probs[n * 8 + e] = p[e]; }
    int i0 = 0;
#pragma unroll
    for (int e = 1; e < 8; e++) if (p[e] > p[i0]) i0 = e;
    int i1 = (i0 == 0) ? 1 : 0;
#pragma unroll
    for (int e = 0; e < 8; e++) if (e != i0 && p[e] > p[i1]) i1 = e;
    float sw = p[i0] + p[i1];
    eids[n * 2] = i0; eids[n * 2 + 1] = i1;
    ewts[n * 2] = p[i0] / sw; ewts[n * 2 + 1] = p[i1] / sw;
  }
}

// ---------------- plan: counts, psum, tile table, aux loss ----------------
// meta: [0..8) cnt, [8..16) cursor, [16..24) tileBase, [24..96) tileExpert, [96] total
__global__ __launch_bounds__(256) void plan_kernel(
    const float* __restrict__ probs, const int* __restrict__ eids,
    float* __restrict__ aux_out, int* __restrict__ meta) {
  __shared__ float pl[256][8];
  __shared__ int cl[256][8];
  __shared__ float ps2[8];
  __shared__ int cn2[8];
  int t = threadIdx.x;
  float pa[8] = {0, 0, 0, 0, 0, 0, 0, 0};
  int ca[8] = {0, 0, 0, 0, 0, 0, 0, 0};
  for (int n = t; n < N_TOK; n += 256) {
#pragma unroll
    for (int e = 0; e < 8; e++) pa[e] += probs[n * 8 + e];
    ca[eids[n * 2]]++; ca[eids[n * 2 + 1]]++;
  }
#pragma unroll
  for (int e = 0; e < 8; e++) { pl[t][e] = pa[e]; cl[t][e] = ca[e]; }
  __syncthreads();
  if (t < 8) {
    float s = 0; int c = 0;
    for (int i = 0; i < 256; i++) { s += pl[i][t]; c += cl[i][t]; }
    ps2[t] = s; cn2[t] = c;
  }
  __syncthreads();
  if (t == 0) {
    int tb = 0; float aux = 0.f;
    for (int e = 0; e < 8; e++) {
      int c = cn2[e];
      meta[e] = c; meta[8 + e] = 0; meta[16 + e] = tb;
      int tiles = (c + 127) >> 7;
      for (int i = 0; i < tiles; i++) meta[24 + tb + i] = e;
      tb += tiles;
      aux += ((float)c / (float)(N_TOK * 2)) * (ps2[e] / (float)N_TOK);
    }
    meta[96] = tb;
    *aux_out = 0.01f * 8.f * aux;
  }
}

// ---------------- scatter tokens into expert-grouped rows + inverse map ----------------
__global__ __launch_bounds__(256) void scatter_kernel(
    const int* __restrict__ eids, int* __restrict__ meta,
    int* __restrict__ perm, int* __restrict__ inv) {
  int n = blockIdx.x * 256 + threadIdx.x;
  if (n >= N_TOK) return;
#pragma unroll
  for (int s = 0; s < 2; s++) {
    int e = eids[n * 2 + s];
    int pos = atomicAdd(&meta[8 + e], 1);
    int row = (meta[16 + e] << 7) + pos;
    perm[row] = n;
    inv[n * 2 + s] = row;
  }
}

// ---------------- transpose + convert: src f32 [R][C] -> dst bf16 [C][R] ----------------
__global__ __launch_bounds__(256) void transpose_conv(
    const float* __restrict__ src, unsigned short* __restrict__ dst, int R, int C) {
  __shared__ unsigned short tile[64 * 64];  // XOR-swizzled 16B chunks
  size_t eoff = (size_t)blockIdx.z * (size_t)R * (size_t)C;
  src += eoff; dst += eoff;
  int c0 = blockIdx.x << 6, r0 = blockIdx.y << 6;
  int t = threadIdx.x;
  int rl = (t >> 4) << 2;
  int cl = (t & 15) << 2;
  f32x4 v[4];
#pragma unroll
  for (int i = 0; i < 4; i++)
    v[i] = *(const f32x4*)(src + (size_t)(r0 + rl + i) * C + c0 + cl);
#pragma unroll
  for (int u = 0; u < 4; u++) {
    int c = cl + u;
    us4 o = {f2bf(v[0][u]), f2bf(v[1][u]), f2bf(v[2][u]), f2bf(v[3][u])};
    unsigned byteoff = (unsigned)c * 128 + ((((unsigned)(rl >> 3)) ^ (unsigned)(c & 7)) << 4) + (unsigned)(rl & 7) * 2;
    *(us4*)((char*)tile + byteoff) = o;
  }
  __syncthreads();
#pragma unroll
  for (int p = 0; p < 2; p++) {
    int id = t + p * 256;
    int c = id >> 3, q = id & 7;
    unsigned byteoff = (unsigned)c * 128 + (((unsigned)q ^ (unsigned)(c & 7)) << 4);
    us8 val = *(const us8*)((const char*)tile + byteoff);
    *(us8*)(dst + (size_t)(c0 + c) * R + r0 + q * 8) = val;
  }
}

// ---------------- GEMM1: 128x128 tile, BK=128 (half the staging drains of r6) ----------------
// LDS 64 KB (2 blocks/CU unchanged); 8 gload16/wave per matrix per K-tile;
// 4 ks-groups x 16 MFMA per K-tile; 16-chunk XOR swizzle (2-way LDS alias = free).
__global__ __launch_bounds__(256, 2) void gemm1_kernel(
    const unsigned short* __restrict__ A,   // bf16 rows, stride 1024 (gathered)
    const unsigned short* __restrict__ Bt,  // bf16 [E][4096][1024]
    unsigned short* __restrict__ Hout,
    const int* __restrict__ perm,
    const int* __restrict__ tileExpert, const int* __restrict__ totalTiles) {
  constexpr int K = DDIM, NB = FDIM;
  __shared__ unsigned short ldsA[128 * 128];  // 32 KB
  __shared__ unsigned short ldsB[128 * 128];  // 32 KB
  int tile = blockIdx.x;
  if (tile >= *totalTiles) return;
  int e = tileExpert[tile];
  int m0 = tile << 7;
  int n0 = blockIdx.y << 7;
  const unsigned short* Bbase = Bt + ((size_t)e * NB + n0) * K;
  int t = threadIdx.x;
  int wave = t >> 6, lane = t & 63;
  int g = lane >> 4, ln = lane & 15;
  int wm = wave >> 1, wn = wave & 1;

  const unsigned short* srcA[8];
  const unsigned short* srcB[8];
#pragma unroll
  for (int i = 0; i < 8; i++) {
    int c = wave * 512 + i * 64 + lane;   // chunk id 0..2047
    int r = c >> 4, kc = c & 15;          // row 0..127, 16B-chunk 0..15
    srcA[i] = A + (size_t)perm[m0 + r] * K + ((kc ^ (r & 7)) << 3);
    srcB[i] = Bbase + (size_t)r * K + ((kc ^ (r & 7)) << 3);
  }

  f32x4 acc[4][4];
#pragma unroll
  for (int a = 0; a < 4; a++)
#pragma unroll
    for (int b = 0; b < 4; b++) acc[a][b] = (f32x4){0.f, 0.f, 0.f, 0.f};

  for (int k0 = 0; k0 < K; k0 += 128) {
#pragma unroll
    for (int i = 0; i < 8; i++) {
      int cb = wave * 512 + i * 64;
      gload16(srcA[i] + k0, &ldsA[cb * 8]);
      gload16(srcB[i] + k0, &ldsB[cb * 8]);
    }
    __syncthreads();
#pragma unroll
    for (int ks = 0; ks < 4; ks++) {
      bf16x8 af[4], bfr[4];
      int q = ks * 4 + g;
#pragma unroll
      for (int mf = 0; mf < 4; mf++) {
        int m = wm * 64 + mf * 16 + ln;
        af[mf] = *(const bf16x8*)((const char*)ldsA + m * 256 + ((q ^ (m & 7)) << 4));
      }
#pragma unroll
      for (int nf = 0; nf < 4; nf++) {
        int n = wn * 64 + nf * 16 + ln;
        bfr[nf] = *(const bf16x8*)((const char*)ldsB + n * 256 + ((q ^ (n & 7)) << 4));
      }
#pragma unroll
      for (int mf = 0; mf < 4; mf++)
#pragma unroll
        for (int nf = 0; nf < 4; nf++)
          acc[mf][nf] = __builtin_amdgcn_mfma_f32_16x16x32_bf16(af[mf], bfr[nf], acc[mf][nf], 0, 0, 0);
    }
    __syncthreads();
  }

#pragma unroll
  for (int mf = 0; mf < 4; mf++) {
#pragma unroll
    for (int r = 0; r < 4; r++) {
      int row = m0 + wm * 64 + mf * 16 + g * 4 + r;
      unsigned short* hp = Hout + (size_t)row * NB + n0 + wn * 64 + ln;
#pragma unroll
      for (int nf = 0; nf < 4; nf++) {
        float v = acc[mf][nf][r];
        v = 0.5f * v * (1.f + erff(v * 0.70710678118654752f));
        hp[nf * 16] = f2bf(v);
      }
    }
  }
}

// ---------------- GEMM2: 128x128 tile, BK=128, K=4096; plain f32 y stores ----------------
__global__ __launch_bounds__(256, 2) void gemm2_kernel(
    const unsigned short* __restrict__ A,   // bf16 rows (h), stride 4096
    const unsigned short* __restrict__ Bt,  // bf16 [E][1024][4096]
    float* __restrict__ Out,                // y scratch [MAXROWS][1024]
    const int* __restrict__ tileExpert, const int* __restrict__ totalTiles) {
  constexpr int K = FDIM, NB = DDIM;
  __shared__ unsigned short ldsA[128 * 128];
  __shared__ unsigned short ldsB[128 * 128];
  int tile = blockIdx.x;
  if (tile >= *totalTiles) return;
  int e = tileExpert[tile];
  int m0 = tile << 7;
  int n0 = blockIdx.y << 7;
  const unsigned short* Bbase = Bt + ((size_t)e * NB + n0) * K;
  int t = threadIdx.x;
  int wave = t >> 6, lane = t & 63;
  int g = lane >> 4, ln = lane & 15;
  int wm = wave >> 1, wn = wave & 1;

  const unsigned short* srcA[8];
  const unsigned short* srcB[8];
#pragma unroll
  for (int i = 0; i < 8; i++) {
    int c = wave * 512 + i * 64 + lane;
    int r = c >> 4, kc = c & 15;
    srcA[i] = A + (size_t)(m0 + r) * K + ((kc ^ (r & 7)) << 3);
    srcB[i] = Bbase + (size_t)r * K + ((kc ^ (r & 7)) << 3);
  }

  f32x4 acc[4][4];
#pragma unroll
  for (int a = 0; a < 4; a++)
#pragma unroll
    for (int b = 0; b < 4; b++) acc[a][b] = (f32x4){0.f, 0.f, 0.f, 0.f};

  for (int k0 = 0; k0 < K; k0 += 128) {
#pragma unroll
    for (int i = 0; i < 8; i++) {
      int cb = wave * 512 + i * 64;
      gload16(srcA[i] + k0, &ldsA[cb * 8]);
      gload16(srcB[i] + k0, &ldsB[cb * 8]);
    }
    __syncthreads();
#pragma unroll
    for (int ks = 0; ks < 4; ks++) {
      bf16x8 af[4], bfr[4];
      int q = ks * 4 + g;
#pragma unroll
      for (int mf = 0; mf < 4; mf++) {
        int m = wm * 64 + mf * 16 + ln;
        af[mf] = *(const bf16x8*)((const char*)ldsA + m * 256 + ((q ^ (m & 7)) << 4));
      }
#pragma unroll
      for (int nf = 0; nf < 4; nf++) {
        int n = wn * 64 + nf * 16 + ln;
        bfr[nf] = *(const bf16x8*)((const char*)ldsB + n * 256 + ((q ^ (n & 7)) << 4));
      }
#pragma unroll
      for (int mf = 0; mf < 4; mf++)
#pragma unroll
        for (int nf = 0; nf < 4; nf++)
          acc[mf][nf] = __builtin_amdgcn_mfma_f32_16x16x32_bf16(af[mf], bfr[nf], acc[mf][nf], 0, 0, 0);
    }
    __syncthreads();
  }

#pragma unroll
  for (int mf = 0; mf < 4; mf++) {
#pragma unroll
    for (int r = 0; r < 4; r++) {
      int row = m0 + wm * 64 + mf * 16 + g * 4 + r;
      float* yp = Out + (size_t)row * NB + n0 + wn * 64 + ln;
#pragma unroll
      for (int nf = 0; nf < 4; nf++) yp[nf * 16] = acc[mf][nf][r];
    }
  }
}

// ---------------- combine: out[n] = w0*y[r0] + w1*y[r1] ----------------
__global__ __launch_bounds__(256) void combine_kernel(
    const float* __restrict__ yscr, const int* __restrict__ inv,
    const float* __restrict__ ewts, float* __restrict__ out) {
  int n = blockIdx.x, t = threadIdx.x;
  int r0 = inv[n * 2], r1 = inv[n * 2 + 1];
  float w0 = ewts[n * 2], w1 = ewts[n * 2 + 1];
  f32x4 a = *(const f32x4*)(yscr + (size_t)r0 * DDIM + t * 4);
  f32x4 b = *(const f32x4*)(yscr + (size_t)r1 * DDIM + t * 4);
  f32x4 o;
#pragma unroll
  for (int j = 0; j < 4; j++) o[j] = w0 * a[j] + w1 * b[j];
  *(f32x4*)(out + (size_t)n * DDIM + t * 4) = o;
}

extern "C" void kernel_launch(void* const* d_in, const int* in_sizes, int n_in,
                              void* d_out, int out_size, void* d_ws, size_t ws_size,
                              hipStream_t stream) {
  const float* x = (const float*)d_in[0];
  const float* wgate = (const float*)d_in[1];
  const float* w1 = (const float*)d_in[2];
  const float* w2 = (const float*)d_in[3];
  float* out = (float*)d_out;

  char* w = (char*)d_ws;
  float* probs = (float*)w;                 w += (size_t)N_TOK * 8 * 4;
  int* eids = (int*)w;                      w += (size_t)N_TOK * 2 * 4;
  float* ewts = (float*)w;                  w += (size_t)N_TOK * 2 * 4;
  int* meta = (int*)w;                      w += 512;
  int* perm = (int*)w;                      w += (size_t)MAXROWS * 4;
  int* inv = (int*)w;                       w += (size_t)N_TOK * 2 * 4;
  unsigned short* xb = (unsigned short*)w;  w += (size_t)N_TOK * DDIM * 2;
  unsigned short* w1t = (unsigned short*)w; w += (size_t)NEXP * DDIM * FDIM * 2;
  unsigned short* w2t = (unsigned short*)w; w += (size_t)NEXP * DDIM * FDIM * 2;
  unsigned short* h = (unsigned short*)w;   w += (size_t)MAXROWS * FDIM * 2;
  // y scratch (MAXROWS x DDIM f32 = 37.75 MB) reuses the w1t region (64 MB),
  // which is dead after GEMM1; rewritten by transpose_conv every replay.
  float* yscr = (float*)w1t;

  hipMemsetAsync(perm, 0, (size_t)MAXROWS * 4, stream);  // padding rows -> token 0

  router_kernel<<<N_TOK, 64, 0, stream>>>(x, wgate, probs, eids, ewts, xb);
  plan_kernel<<<1, 256, 0, stream>>>(probs, eids, out + 4194304, meta);
  scatter_kernel<<<16, 256, 0, stream>>>(eids, meta, perm, inv);
  transpose_conv<<<dim3(64, 16, 8), 256, 0, stream>>>(w1, w1t, DDIM, FDIM);
  transpose_conv<<<dim3(16, 64, 8), 256, 0, stream>>>(w2, w2t, FDIM, DDIM);
  // GEMM1: gathered rows x [1024] @ [1024 x 4096]/expert -> h (gelu, bf16)
  gemm1_kernel<<<dim3(MAXT, 32), 256, 0, stream>>>(
      xb, w1t, h, perm, meta + 24, meta + 96);
  // GEMM2: rows x [4096] @ [4096 x 1024]/expert -> yscr (plain f32 stores)
  gemm2_kernel<<<dim3(MAXT, 8), 256, 0, stream>>>(
      h, w2t, yscr, meta + 24, meta + 96);
  // weighted top-2 combine (deterministic, replaces atomic scatter)
  combine_kernel<<<N_TOK, 256, 0, stream>>>(yscr, inv, ewts, out);
}

// Round 13
// 388.517 us; speedup vs baseline: 1.1392x; 1.1392x over previous
//
#include <hip/hip_runtime.h>
#include <cmath>

#define N_TOK 4096
#define DDIM 1024
#define FDIM 4096
#define NEXP 8
#define MAXT 72
#define MAXROWS (MAXT * 128)

typedef __attribute__((ext_vector_type(4))) float f32x4;
typedef __attribute__((ext_vector_type(8))) __bf16 bf16x8;
typedef __attribute__((ext_vector_type(4))) unsigned short us4;
typedef __attribute__((ext_vector_type(8))) unsigned short us8;

__device__ __forceinline__ unsigned short f2bf(float f) {
  unsigned u = __builtin_bit_cast(unsigned, f);
  u += 0x7FFFu + ((u >> 16) & 1u);
  return (unsigned short)(u >> 16);
}

__device__ __forceinline__ void gload16(const void* g, void* l) {
  __builtin_amdgcn_global_load_lds(
      (const __attribute__((address_space(1))) unsigned int*)g,
      (__attribute__((address_space(3))) unsigned int*)l, 16, 0, 0);
}

// m204 bijective XCD remap: hw id (round-robin over 8 XCDs) -> logical id so
// each XCD owns a contiguous logical chunk.
__device__ __forceinline__ int xcd_remap(int h, int nwg) {
  int q = nwg >> 3, r = nwg & 7;
  int xcd = h & 7, o = h >> 3;
  return (xcd < r ? xcd * (q + 1) : r * (q + 1) + (xcd - r) * q) + o;
}

// ---------------- router: logits -> softmax -> top2 (+ fused x->bf16) ----------------
__global__ __launch_bounds__(64) void router_kernel(
    const float* __restrict__ x, const float* __restrict__ wg,
    float* __restrict__ probs, int* __restrict__ eids, float* __restrict__ ewts,
    unsigned short* __restrict__ xb) {
  int n = blockIdx.x;
  int t = threadIdx.x;
  const float* xr = x + (size_t)n * DDIM;
  f32x4 xv[4];
#pragma unroll
  for (int j = 0; j < 4; j++) xv[j] = *(const f32x4*)(xr + j * 256 + t * 4);
  float acc[8] = {0, 0, 0, 0, 0, 0, 0, 0};
#pragma unroll
  for (int j = 0; j < 4; j++) {
#pragma unroll
    for (int u = 0; u < 4; u++) {
      float v = xv[j][u];
      const float* wr = wg + (size_t)(j * 256 + t * 4 + u) * 8;
#pragma unroll
      for (int e = 0; e < 8; e++) acc[e] = fmaf(v, wr[e], acc[e]);
    }
  }
  unsigned short* xo = xb + (size_t)n * DDIM;
#pragma unroll
  for (int j = 0; j < 4; j++) {
    us4 o = {f2bf(xv[j][0]), f2bf(xv[j][1]), f2bf(xv[j][2]), f2bf(xv[j][3])};
    *(us4*)(xo + j * 256 + t * 4) = o;
  }
#pragma unroll
  for (int off = 32; off > 0; off >>= 1) {
#pragma unroll
    for (int e = 0; e < 8; e++) acc[e] += __shfl_xor(acc[e], off, 64);
  }
  if (t == 0) {
    float mx = acc[0];
#pragma unroll
    for (int e = 1; e < 8; e++) mx = fmaxf(mx, acc[e]);
    float p[8], s = 0.f;
#pragma unroll
    for (int e = 0; e < 8; e++) { p[e] = expf(acc[e] - mx); s += p[e]; }
    float inv = 1.f / s;
#pragma unroll
    for (int e = 0; e < 8; e++) { p[e] *= inv; probs[n * 8 + e] = p[e]; }
    int i0 = 0;
#pragma unroll
    for (int e = 1; e < 8; e++) if (p[e] > p[i0]) i0 = e;
    int i1 = (i0 == 0) ? 1 : 0;
#pragma unroll
    for (int e = 0; e < 8; e++) if (e != i0 && p[e] > p[i1]) i1 = e;
    float sw = p[i0] + p[i1];
    eids[n * 2] = i0; eids[n * 2 + 1] = i1;
    ewts[n * 2] = p[i0] / sw; ewts[n * 2 + 1] = p[i1] / sw;
  }
}

// ---------------- plan: counts, psum, tile table, aux loss ----------------
// meta: [0..8) cnt, [8..16) cursor, [16..24) tileBase, [24..96) tileExpert, [96] total
__global__ __launch_bounds__(256) void plan_kernel(
    const float* __restrict__ probs, const int* __restrict__ eids,
    float* __restrict__ aux_out, int* __restrict__ meta) {
  __shared__ float pl[256][8];
  __shared__ int cl[256][8];
  __shared__ float ps2[8];
  __shared__ int cn2[8];
  int t = threadIdx.x;
  float pa[8] = {0, 0, 0, 0, 0, 0, 0, 0};
  int ca[8] = {0, 0, 0, 0, 0, 0, 0, 0};
  for (int n = t; n < N_TOK; n += 256) {
#pragma unroll
    for (int e = 0; e < 8; e++) pa[e] += probs[n * 8 + e];
    ca[eids[n * 2]]++; ca[eids[n * 2 + 1]]++;
  }
#pragma unroll
  for (int e = 0; e < 8; e++) { pl[t][e] = pa[e]; cl[t][e] = ca[e]; }
  __syncthreads();
  if (t < 8) {
    float s = 0; int c = 0;
    for (int i = 0; i < 256; i++) { s += pl[i][t]; c += cl[i][t]; }
    ps2[t] = s; cn2[t] = c;
  }
  __syncthreads();
  if (t == 0) {
    int tb = 0; float aux = 0.f;
    for (int e = 0; e < 8; e++) {
      int c = cn2[e];
      meta[e] = c; meta[8 + e] = 0; meta[16 + e] = tb;
      int tiles = (c + 127) >> 7;
      for (int i = 0; i < tiles; i++) meta[24 + tb + i] = e;
      tb += tiles;
      aux += ((float)c / (float)(N_TOK * 2)) * (ps2[e] / (float)N_TOK);
    }
    meta[96] = tb;
    *aux_out = 0.01f * 8.f * aux;
  }
}

// ---------------- scatter tokens into expert-grouped rows + inverse map ----------------
__global__ __launch_bounds__(256) void scatter_kernel(
    const int* __restrict__ eids, int* __restrict__ meta,
    int* __restrict__ perm, int* __restrict__ inv) {
  int n = blockIdx.x * 256 + threadIdx.x;
  if (n >= N_TOK) return;
#pragma unroll
  for (int s = 0; s < 2; s++) {
    int e = eids[n * 2 + s];
    int pos = atomicAdd(&meta[8 + e], 1);
    int row = (meta[16 + e] << 7) + pos;
    perm[row] = n;
    inv[n * 2 + s] = row;
  }
}

// ---------------- transpose + convert: src f32 [R][C] -> dst bf16 [C][R] ----------------
__global__ __launch_bounds__(256) void transpose_conv(
    const float* __restrict__ src, unsigned short* __restrict__ dst, int R, int C) {
  __shared__ unsigned short tile[64 * 64];  // XOR-swizzled 16B chunks
  size_t eoff = (size_t)blockIdx.z * (size_t)R * (size_t)C;
  src += eoff; dst += eoff;
  int c0 = blockIdx.x << 6, r0 = blockIdx.y << 6;
  int t = threadIdx.x;
  int rl = (t >> 4) << 2;
  int cl = (t & 15) << 2;
  f32x4 v[4];
#pragma unroll
  for (int i = 0; i < 4; i++)
    v[i] = *(const f32x4*)(src + (size_t)(r0 + rl + i) * C + c0 + cl);
#pragma unroll
  for (int u = 0; u < 4; u++) {
    int c = cl + u;
    us4 o = {f2bf(v[0][u]), f2bf(v[1][u]), f2bf(v[2][u]), f2bf(v[3][u])};
    unsigned byteoff = (unsigned)c * 128 + ((((unsigned)(rl >> 3)) ^ (unsigned)(c & 7)) << 4) + (unsigned)(rl & 7) * 2;
    *(us4*)((char*)tile + byteoff) = o;
  }
  __syncthreads();
#pragma unroll
  for (int p = 0; p < 2; p++) {
    int id = t + p * 256;
    int c = id >> 3, q = id & 7;
    unsigned byteoff = (unsigned)c * 128 + (((unsigned)q ^ (unsigned)(c & 7)) << 4);
    us8 val = *(const us8*)((const char*)tile + byteoff);
    *(us8*)(dst + (size_t)(c0 + c) * R + r0 + q * 8) = val;
  }
}

// ---------------- grouped GEMM: 128x128 tile, BK=64, 16x16x32 bf16 MFMA ----------------
// r7 configuration (best measured total): 1-D grid, XCD-chunked (m204)
// 8mt x 4nt supertiles (A 2 MB + B <=2 MB fits 4 MB per-XCD L2).
// MODE 1: gelu -> bf16 h. MODE 2: plain f32 y store (no atomics).
template <int K, int NPANELS, bool GATHER, int MODE>
__global__ __launch_bounds__(256, 2) void gemm_kernel(
    const unsigned short* __restrict__ A,   // bf16 rows, stride K
    const unsigned short* __restrict__ Bt,  // bf16 [E][NB][K]
    unsigned short* __restrict__ Hout,
    float* __restrict__ Out,
    const int* __restrict__ perm,
    const int* __restrict__ tileExpert, const int* __restrict__ totalTiles,
    int NB) {
  __shared__ unsigned short ldsA[128 * 64];
  __shared__ unsigned short ldsB[128 * 64];
  constexpr int NWG = MAXT * NPANELS;
  int L = xcd_remap((int)blockIdx.x, NWG);
  int sup = L >> 5, wi = L & 31;          // 8mt x 4nt supertile, mt fastest
  constexpr int GM = MAXT / 8;            // 9
  int gm = sup % GM, gn = sup / GM;
  int tile = gm * 8 + (wi & 7);
  int nt = gn * 4 + (wi >> 3);
  if (tile >= *totalTiles) return;
  int e = tileExpert[tile];
  int m0 = tile << 7;
  int n0 = nt << 7;
  const unsigned short* Bbase = Bt + ((size_t)e * NB + n0) * K;
  int t = threadIdx.x;
  int wave = t >> 6, lane = t & 63;
  int g = lane >> 4, ln = lane & 15;
  int wm = wave >> 1, wn = wave & 1;

  const unsigned short* srcA[4];
  const unsigned short* srcB[4];
#pragma unroll
  for (int i = 0; i < 4; i++) {
    int c = wave * 256 + i * 64 + lane;
    int r = c >> 3, kc = c & 7;
    int rowA = GATHER ? perm[m0 + r] : (m0 + r);
    srcA[i] = A + (size_t)rowA * K + ((kc ^ (r & 7)) << 3);
    srcB[i] = Bbase + (size_t)r * K + ((kc ^ (r & 7)) << 3);
  }

  f32x4 acc[4][4];
#pragma unroll
  for (int a = 0; a < 4; a++)
#pragma unroll
    for (int b = 0; b < 4; b++) acc[a][b] = (f32x4){0.f, 0.f, 0.f, 0.f};

  for (int k0 = 0; k0 < K; k0 += 64) {
#pragma unroll
    for (int i = 0; i < 4; i++) {
      int cb = wave * 256 + i * 64;
      gload16(srcA[i] + k0, &ldsA[cb * 8]);
      gload16(srcB[i] + k0, &ldsB[cb * 8]);
    }
    __syncthreads();
#pragma unroll
    for (int ks = 0; ks < 2; ks++) {
      bf16x8 af[4], bfr[4];
      int q = ks * 4 + g;
#pragma unroll
      for (int mf = 0; mf < 4; mf++) {
        int m = wm * 64 + mf * 16 + ln;
        af[mf] = *(const bf16x8*)((const char*)ldsA + m * 128 + ((q ^ (m & 7)) << 4));
      }
#pragma unroll
      for (int nf = 0; nf < 4; nf++) {
        int n = wn * 64 + nf * 16 + ln;
        bfr[nf] = *(const bf16x8*)((const char*)ldsB + n * 128 + ((q ^ (n & 7)) << 4));
      }
#pragma unroll
      for (int mf = 0; mf < 4; mf++)
#pragma unroll
        for (int nf = 0; nf < 4; nf++)
          acc[mf][nf] = __builtin_amdgcn_mfma_f32_16x16x32_bf16(af[mf], bfr[nf], acc[mf][nf], 0, 0, 0);
    }
    __syncthreads();
  }

  if (MODE == 1) {
#pragma unroll
    for (int mf = 0; mf < 4; mf++) {
#pragma unroll
      for (int r = 0; r < 4; r++) {
        int row = m0 + wm * 64 + mf * 16 + g * 4 + r;
        unsigned short* hp = Hout + (size_t)row * NB + n0 + wn * 64 + ln;
#pragma unroll
        for (int nf = 0; nf < 4; nf++) {
          float v = acc[mf][nf][r];
          v = 0.5f * v * (1.f + erff(v * 0.70710678118654752f));
          hp[nf * 16] = f2bf(v);
        }
      }
    }
  } else {
#pragma unroll
    for (int mf = 0; mf < 4; mf++) {
#pragma unroll
      for (int r = 0; r < 4; r++) {
        int row = m0 + wm * 64 + mf * 16 + g * 4 + r;
        float* yp = Out + (size_t)row * NB + n0 + wn * 64 + ln;
#pragma unroll
        for (int nf = 0; nf < 4; nf++) yp[nf * 16] = acc[mf][nf][r];
      }
    }
  }
}

// ---------------- combine: out[n] = w0*y[r0] + w1*y[r1] ----------------
__global__ __launch_bounds__(256) void combine_kernel(
    const float* __restrict__ yscr, const int* __restrict__ inv,
    const float* __restrict__ ewts, float* __restrict__ out) {
  int n = blockIdx.x, t = threadIdx.x;
  int r0 = inv[n * 2], r1 = inv[n * 2 + 1];
  float w0 = ewts[n * 2], w1 = ewts[n * 2 + 1];
  f32x4 a = *(const f32x4*)(yscr + (size_t)r0 * DDIM + t * 4);
  f32x4 b = *(const f32x4*)(yscr + (size_t)r1 * DDIM + t * 4);
  f32x4 o;
#pragma unroll
  for (int j = 0; j < 4; j++) o[j] = w0 * a[j] + w1 * b[j];
  *(f32x4*)(out + (size_t)n * DDIM + t * 4) = o;
}

extern "C" void kernel_launch(void* const* d_in, const int* in_sizes, int n_in,
                              void* d_out, int out_size, void* d_ws, size_t ws_size,
                              hipStream_t stream) {
  const float* x = (const float*)d_in[0];
  const float* wgate = (const float*)d_in[1];
  const float* w1 = (const float*)d_in[2];
  const float* w2 = (const float*)d_in[3];
  float* out = (float*)d_out;

  char* w = (char*)d_ws;
  float* probs = (float*)w;                 w += (size_t)N_TOK * 8 * 4;
  int* eids = (int*)w;                      w += (size_t)N_TOK * 2 * 4;
  float* ewts = (float*)w;                  w += (size_t)N_TOK * 2 * 4;
  int* meta = (int*)w;                      w += 512;
  int* perm = (int*)w;                      w += (size_t)MAXROWS * 4;
  int* inv = (int*)w;                       w += (size_t)N_TOK * 2 * 4;
  unsigned short* xb = (unsigned short*)w;  w += (size_t)N_TOK * DDIM * 2;
  unsigned short* w1t = (unsigned short*)w; w += (size_t)NEXP * DDIM * FDIM * 2;
  unsigned short* w2t = (unsigned short*)w; w += (size_t)NEXP * DDIM * FDIM * 2;
  unsigned short* h = (unsigned short*)w;   w += (size_t)MAXROWS * FDIM * 2;
  // y scratch (MAXROWS x DDIM f32 = 37.75 MB) reuses the w1t region (64 MB),
  // which is dead after GEMM1; rewritten by transpose_conv every replay.
  float* yscr = (float*)w1t;

  hipMemsetAsync(perm, 0, (size_t)MAXROWS * 4, stream);  // padding rows -> token 0

  router_kernel<<<N_TOK, 64, 0, stream>>>(x, wgate, probs, eids, ewts, xb);
  plan_kernel<<<1, 256, 0, stream>>>(probs, eids, out + 4194304, meta);
  scatter_kernel<<<16, 256, 0, stream>>>(eids, meta, perm, inv);
  transpose_conv<<<dim3(64, 16, 8), 256, 0, stream>>>(w1, w1t, DDIM, FDIM);
  transpose_conv<<<dim3(16, 64, 8), 256, 0, stream>>>(w2, w2t, FDIM, DDIM);
  // GEMM1: gathered rows x [1024] @ [1024 x 4096]/expert -> h (gelu, bf16)
  gemm_kernel<DDIM, 32, true, 1><<<MAXT * 32, 256, 0, stream>>>(
      xb, w1t, h, nullptr, perm, meta + 24, meta + 96, FDIM);
  // GEMM2: rows x [4096] @ [4096 x 1024]/expert -> yscr (plain f32 stores)
  gemm_kernel<FDIM, 8, false, 2><<<MAXT * 8, 256, 0, stream>>>(
      h, w2t, nullptr, yscr, perm, meta + 24, meta + 96, DDIM);
  // weighted top-2 combine (deterministic, replaces atomic scatter)
  combine_kernel<<<N_TOK, 256, 0, stream>>>(yscr, inv, ewts, out);
}